// Round 5
// baseline (31.134 us; speedup 1.0000x reference)
//
#include <hip/hip_runtime.h>
#include <hip/hip_bf16.h>

constexpr int L_LEN = 4096;
constexpr int CH = 8;          // channels
constexpr int S_SAMPLES = 256; // continuous start samples
constexpr int K_SAMP = 32;     // shapelet samples
constexpr int NSHAPE = 16;
constexpr int NB = 32;         // batch
constexpr int NPB = 2;                  // p values per block
constexpr int NPBLK = S_SAMPLES / NPB;  // 128 p-blocks
constexpr int THREADS = 256;            // b(32) x pl(2) x quarter(4 waves)
constexpr int NSAMP = K_SAMP / 4 + 1;   // 9 samples per thread

// path (B,L,C) -> ws (L,B,C); write-coalesced, reads scatter (one-time 4MB)
__global__ __launch_bounds__(256) void transpose_kernel(const float4* __restrict__ src,
                                                        float4* __restrict__ dst) {
    const int t  = blockIdx.x * 256 + threadIdx.x;  // 262144 float4s
    const int c4 = t & 1;
    const int b  = (t >> 1) & (NB - 1);
    const int l  = t >> 6;
    dst[t] = src[(b * L_LEN + l) * 2 + c4];
}

// tid bits: [0:4]=b, [5]=pl, [6:7]=quarter (whole wave per quarter)
__global__ __launch_bounds__(THREADS, 3) void shapelet_min_kernel(
    const float* __restrict__ wst,       // (L, B, C) transposed path
    const float* __restrict__ lengths,   // (NSHAPE)
    const float* __restrict__ shapelets, // (NSHAPE, K, C)
    float* __restrict__ partial)         // (NSHAPE, NPBLK, NB)
{
    __shared__ float sred[4][64];        // [quarter][pl*32+b]

    const int s   = blockIdx.y;
    const int tid = threadIdx.x;
    const int b   = tid & (NB - 1);
    const int pl  = (tid >> 5) & 1;
    const int quarter = __builtin_amdgcn_readfirstlane(tid >> 6); // wave-uniform
    const int p   = blockIdx.x * NPB + pl;       // 0..255

    const float len   = fminf(fmaxf(lengths[s], 0.01f), 512.0f);
    const float start = ((float)p / (float)(S_SAMPLES - 1)) * ((float)(L_LEN - 1) - len);
    const float step  = len * (1.0f / (float)(K_SAMP - 1));
    const int   k0    = quarter * (K_SAMP / 4);  // 0, 8, 16, 24

    const float4* __restrict__ w4  = reinterpret_cast<const float4*>(wst);
    const float*  __restrict__ shp = shapelets + s * K_SAMP * CH; // wave-uniform rows

    // precompute all sample addresses (q >= 0 so (int)q == floor(q))
    int   base[NSAMP];
    float rr[NSAMP];
    #pragma unroll
    for (int i = 0; i < NSAMP; ++i) {
        const int   kk  = min(k0 + i, K_SAMP - 1);
        const float q   = start + (float)kk * step;
        const int   idx = min((int)q, L_LEN - 2);
        rr[i]   = q - (float)idx;
        base[i] = (idx * NB + b) * 2;
    }

    // 4-slot software pipeline: load sample i+3 while computing sample i
    float4 buf[4][4];
    #pragma unroll
    for (int i = 0; i < 3; ++i) {
        buf[i][0] = w4[base[i] + 0];
        buf[i][1] = w4[base[i] + 1];
        buf[i][2] = w4[base[i] + 2 * NB + 0];
        buf[i][3] = w4[base[i] + 2 * NB + 1];
    }

    float dprev[CH];
    #pragma unroll
    for (int c = 0; c < CH; ++c) dprev[c] = 0.f;
    float sqprev = 0.f, segsum = 0.f;

    #pragma unroll
    for (int i = 0; i < NSAMP; ++i) {
        if (i + 3 < NSAMP) {
            const int j = i + 3;
            buf[j & 3][0] = w4[base[j] + 0];
            buf[j & 3][1] = w4[base[j] + 1];
            buf[j & 3][2] = w4[base[j] + 2 * NB + 0];
            buf[j & 3][3] = w4[base[j] + 2 * NB + 1];
        }
        const int   kk = min(k0 + i, K_SAMP - 1);
        const float r  = rr[i];
        const float4 a0 = buf[i & 3][0], a1 = buf[i & 3][1];
        const float4 c0 = buf[i & 3][2], c1 = buf[i & 3][3];
        const float pv[CH] = {a0.x, a0.y, a0.z, a0.w, a1.x, a1.y, a1.z, a1.w};
        const float nv[CH] = {c0.x, c0.y, c0.z, c0.w, c1.x, c1.y, c1.z, c1.w};

        float sq = 0.f, dot = 0.f;
        float d[CH];
        #pragma unroll
        for (int c = 0; c < CH; ++c) {
            const float samp = pv[c] + r * (nv[c] - pv[c]);
            d[c] = samp - shp[kk * CH + c];   // wave-uniform -> scalar load
            sq  += d[c] * d[c];
            dot += dprev[c] * d[c];
        }
        if (i > 0) {
            const float w = (k0 + i <= K_SAMP - 1) ? 1.0f : 0.0f;
            segsum += w * (sqprev + dot + sq);
        }
        sqprev = sq;
        #pragma unroll
        for (int c = 0; c < CH; ++c) dprev[c] = d[c];
    }

    sred[quarter][tid & 63] = segsum;
    __syncthreads();

    if (tid < 64) {
        const float tot = sred[0][tid] + sred[1][tid] + sred[2][tid] + sred[3][tid];
        float integral = len * (1.0f / (3.0f * (float)(K_SAMP - 1))) * tot;
        integral = fmaxf(integral, 0.0f);
        // min over the block's two p values (lane bit 5)
        const float m = fminf(integral, __shfl_xor(integral, 32));
        if (tid < NB)
            partial[(s * NPBLK + blockIdx.x) * NB + tid] = m;
    }
}

// one block per shapelet; 256 threads = b(32) x chunk(8)
__global__ __launch_bounds__(256) void shapelet_finalize_kernel(
    const float* __restrict__ partial, float* __restrict__ out)
{
    __shared__ float fred[8][NB];
    const int s     = blockIdx.x;
    const int tid   = threadIdx.x;
    const int b     = tid & (NB - 1);
    const int chunk = tid >> 5;                   // 0..7
    float m = 3.4e38f;
    #pragma unroll
    for (int j = 0; j < NPBLK / 8; ++j) {
        const int pb = chunk * (NPBLK / 8) + j;
        m = fminf(m, partial[(s * NPBLK + pb) * NB + b]);
    }
    fred[chunk][b] = m;
    __syncthreads();
    if (tid < NB) {
        float mm = fred[0][tid];
        #pragma unroll
        for (int j = 1; j < 8; ++j) mm = fminf(mm, fred[j][tid]);
        out[tid * NSHAPE + s] = sqrtf(fmaxf(mm, 1e-12f));
    }
}

extern "C" void kernel_launch(void* const* d_in, const int* in_sizes, int n_in,
                              void* d_out, int out_size, void* d_ws, size_t ws_size,
                              hipStream_t stream) {
    // inputs: times (L), path (B,L,C), lengths (NSHAPE), shapelets (NSHAPE,K,C)
    const float* path      = (const float*)d_in[1];
    const float* lengths   = (const float*)d_in[2];
    const float* shapelets = (const float*)d_in[3];
    float* out = (float*)d_out;

    float* wst     = (float*)d_ws;                                        // 4 MB
    float* partial = (float*)((char*)d_ws + (size_t)L_LEN * NB * CH * 4); // 256 KB

    transpose_kernel<<<L_LEN * NB * CH / 4 / 256, 256, 0, stream>>>(
        (const float4*)path, (float4*)wst);
    dim3 grid(NPBLK, NSHAPE);
    shapelet_min_kernel<<<grid, THREADS, 0, stream>>>(wst, lengths, shapelets, partial);
    shapelet_finalize_kernel<<<NSHAPE, 256, 0, stream>>>(partial, out);
}

// Round 6
// 22.927 us; speedup vs baseline: 1.3580x; 1.3580x over previous
//
#include <hip/hip_runtime.h>
#include <hip/hip_bf16.h>

constexpr int L_LEN = 4096;
constexpr int CH = 8;          // channels
constexpr int S_SAMPLES = 256; // continuous start samples
constexpr int K_SAMP = 32;     // shapelet samples
constexpr int NSHAPE = 16;
constexpr int NB = 32;         // batch
constexpr int NPB = 2;                  // p values per block
constexpr int NPBLK = S_SAMPLES / NPB;  // 128 p-blocks
constexpr int THREADS = 256;            // b(32) x quarter(4) x pl(2)

__device__ __forceinline__ float bf_lo(unsigned u) { return __uint_as_float(u << 16); }
__device__ __forceinline__ float bf_hi(unsigned u) { return __uint_as_float(u & 0xffff0000u); }
__device__ __forceinline__ unsigned short f2bf(float f) {
    unsigned u = __float_as_uint(f);
    u = (u + 0x7fffu + ((u >> 16) & 1u)) >> 16;   // RNE (inputs are finite)
    return (unsigned short)u;
}

// path (B,L,C) f32 -> ws (L,B,C) bf16; one thread per (l,b) row of 8 ch
__global__ __launch_bounds__(256) void transpose_kernel(const float4* __restrict__ src,
                                                        uint4* __restrict__ dst) {
    const int t = blockIdx.x * 256 + threadIdx.x;  // 131072 = L*B
    const int b = t & (NB - 1);
    const int l = t >> 5;
    const float4 f0 = src[(b * L_LEN + l) * 2 + 0];
    const float4 f1 = src[(b * L_LEN + l) * 2 + 1];
    uint4 o;
    o.x = (unsigned)f2bf(f0.x) | ((unsigned)f2bf(f0.y) << 16);
    o.y = (unsigned)f2bf(f0.z) | ((unsigned)f2bf(f0.w) << 16);
    o.z = (unsigned)f2bf(f1.x) | ((unsigned)f2bf(f1.y) << 16);
    o.w = (unsigned)f2bf(f1.z) | ((unsigned)f2bf(f1.w) << 16);
    dst[t] = o;   // 16B per (l,b), coalesced
}

// tid bits: [0:4]=b, [5]=q_lo, [6]=q_hi, [7]=pl  (quarter = bits 5:6)
__global__ __launch_bounds__(THREADS) void shapelet_min_kernel(
    const uint4* __restrict__ wst,       // (L, B, C/2) bf16-packed path
    const float* __restrict__ lengths,   // (NSHAPE)
    const float* __restrict__ shapelets, // (NSHAPE, K, C)
    float* __restrict__ partial)         // (NSHAPE, NPBLK, NB)
{
    __shared__ float sh[K_SAMP][CH + 1]; // stride 9 floats -> conflict-free
    __shared__ float sred[NPB][2][NB];   // [pl][q_hi][b]

    const int s       = blockIdx.y;
    const int tid     = threadIdx.x;
    const int b       = tid & (NB - 1);
    const int quarter = (tid >> 5) & 3;
    const int q_hi    = (tid >> 6) & 1;
    const int pl      = tid >> 7;                  // 0..1
    const int p       = blockIdx.x * NPB + pl;     // 0..255

    sh[tid >> 3][tid & 7] = shapelets[s * K_SAMP * CH + tid];  // 256 == K*CH
    __syncthreads();

    const float len   = fminf(fmaxf(lengths[s], 0.01f), 512.0f);
    const float start = ((float)p / (float)(S_SAMPLES - 1)) * ((float)(L_LEN - 1) - len);
    const float step  = len * (1.0f / (float)(K_SAMP - 1));
    const int   k0    = quarter * (K_SAMP / 4);    // 0, 8, 16, 24

    float dprev[CH];
    float sqprev = 0.f, segsum = 0.f;

    // sample i = 0 (k = k0); q >= 0 so (int)q == floor(q)
    {
        const float q = start + (float)k0 * step;
        const int idx = min(max((int)q, 0), L_LEN - 2);
        const float r = q - (float)idx;
        const int base = idx * NB + b;
        const uint4 A = wst[base];
        const uint4 C = wst[base + NB];
        const float pv[CH] = {bf_lo(A.x), bf_hi(A.x), bf_lo(A.y), bf_hi(A.y),
                              bf_lo(A.z), bf_hi(A.z), bf_lo(A.w), bf_hi(A.w)};
        const float nv[CH] = {bf_lo(C.x), bf_hi(C.x), bf_lo(C.y), bf_hi(C.y),
                              bf_lo(C.z), bf_hi(C.z), bf_lo(C.w), bf_hi(C.w)};
        float sq = 0.f;
        #pragma unroll
        for (int c = 0; c < CH; ++c) {
            const float samp = pv[c] + r * (nv[c] - pv[c]);
            const float d = samp - sh[k0][c];
            dprev[c] = d;
            sq += d * d;
        }
        sqprev = sq;
    }

    // segments i = 1..8 (sample k = k0+i); quarter 3's i=8 (k=32) weighted 0
    #pragma unroll 4
    for (int i = 1; i <= K_SAMP / 4; ++i) {
        const int k  = k0 + i;
        const int kk = min(k, K_SAMP - 1);
        const float w = (k <= K_SAMP - 1) ? 1.0f : 0.0f;

        const float q = start + (float)kk * step;
        const int idx = min(max((int)q, 0), L_LEN - 2);
        const float r = q - (float)idx;
        const int base = idx * NB + b;
        const uint4 A = wst[base];
        const uint4 C = wst[base + NB];
        const float pv[CH] = {bf_lo(A.x), bf_hi(A.x), bf_lo(A.y), bf_hi(A.y),
                              bf_lo(A.z), bf_hi(A.z), bf_lo(A.w), bf_hi(A.w)};
        const float nv[CH] = {bf_lo(C.x), bf_hi(C.x), bf_lo(C.y), bf_hi(C.y),
                              bf_lo(C.z), bf_hi(C.z), bf_lo(C.w), bf_hi(C.w)};

        float sq = 0.f, dot = 0.f;
        float d[CH];
        #pragma unroll
        for (int c = 0; c < CH; ++c) {
            const float samp = pv[c] + r * (nv[c] - pv[c]);
            d[c] = samp - sh[kk][c];
            sq  += d[c] * d[c];
            dot += dprev[c] * d[c];
        }
        segsum += w * (sqprev + dot + sq);
        sqprev = sq;
        #pragma unroll
        for (int c = 0; c < CH; ++c) dprev[c] = d[c];
    }

    // combine quarter pairs (lane bit 5, same wave)
    segsum += __shfl_xor(segsum, 32);
    if ((tid & 32) == 0) sred[pl][q_hi][b] = segsum;
    __syncthreads();

    if (tid < 64) {
        const int bb  = tid & (NB - 1);
        const int plx = tid >> 5;
        const float tot = sred[plx][0][bb] + sred[plx][1][bb];
        float integral = len * (1.0f / (3.0f * (float)(K_SAMP - 1))) * tot;
        integral = fmaxf(integral, 0.0f);
        // min over the block's two p values (lane bit 5)
        const float m = fminf(integral, __shfl_xor(integral, 32));
        if (tid < NB)
            partial[(s * NPBLK + blockIdx.x) * NB + bb] = m;
    }
}

// one block per shapelet; 256 threads = b(32) x chunk(8)
__global__ __launch_bounds__(256) void shapelet_finalize_kernel(
    const float* __restrict__ partial, float* __restrict__ out)
{
    __shared__ float fred[8][NB];
    const int s     = blockIdx.x;
    const int tid   = threadIdx.x;
    const int b     = tid & (NB - 1);
    const int chunk = tid >> 5;                   // 0..7
    float m = 3.4e38f;
    #pragma unroll
    for (int j = 0; j < NPBLK / 8; ++j) {
        const int pb = chunk * (NPBLK / 8) + j;
        m = fminf(m, partial[(s * NPBLK + pb) * NB + b]);
    }
    fred[chunk][b] = m;
    __syncthreads();
    if (tid < NB) {
        float mm = fred[0][tid];
        #pragma unroll
        for (int j = 1; j < 8; ++j) mm = fminf(mm, fred[j][tid]);
        out[tid * NSHAPE + s] = sqrtf(fmaxf(mm, 1e-12f));
    }
}

extern "C" void kernel_launch(void* const* d_in, const int* in_sizes, int n_in,
                              void* d_out, int out_size, void* d_ws, size_t ws_size,
                              hipStream_t stream) {
    // inputs: times (L), path (B,L,C), lengths (NSHAPE), shapelets (NSHAPE,K,C)
    const float* path      = (const float*)d_in[1];
    const float* lengths   = (const float*)d_in[2];
    const float* shapelets = (const float*)d_in[3];
    float* out = (float*)d_out;

    uint4* wst     = (uint4*)d_ws;                                        // 2 MB
    float* partial = (float*)((char*)d_ws + (size_t)L_LEN * NB * 16);     // 256 KB

    transpose_kernel<<<L_LEN * NB / 256, 256, 0, stream>>>(
        (const float4*)path, wst);
    dim3 grid(NPBLK, NSHAPE);
    shapelet_min_kernel<<<grid, THREADS, 0, stream>>>(wst, lengths, shapelets, partial);
    shapelet_finalize_kernel<<<NSHAPE, 256, 0, stream>>>(partial, out);
}